// Round 2
// baseline (1057.694 us; speedup 1.0000x reference)
//
#include <hip/hip_runtime.h>
#include <math.h>

#define NUM_EMB 8192
#define DIM     64
#define NBATCH  4
#define NVOX    32768
#define TPB     256
#define SPLIT   8                 // codebook splits per voxel-block
#define EPB     (NUM_EMB / SPLIT) // 1024 entries per split
#define CHUNK   128               // entries staged in LDS per iteration

// output layout (f32, concatenated in return order)
#define OFF_Q     0            // 32768*64
#define OFF_VQ    2097152
#define OFF_COMM  2097153
#define OFF_IDX   2097154      // 32768
#define OFF_PERP  2129922
#define OFF_ENT   2129923
#define OFF_UNIQ  2129924
#define OFF_UTIL  2129925

// monotone float -> sortable uint (all non-NaN)
__device__ __forceinline__ unsigned fmap(float f) {
    unsigned u = __float_as_uint(f);
    return (u & 0x80000000u) ? ~u : (u | 0x80000000u);
}

__global__ void cnorm_kernel(const float* __restrict__ cb, float* __restrict__ cn) {
    int e = blockIdx.x * blockDim.x + threadIdx.x;
    const float4* row = (const float4*)(cb + (size_t)e * DIM);
    float s = 0.f;
#pragma unroll
    for (int i = 0; i < DIM / 4; ++i) {
        float4 v = row[i];
        s += v.x * v.x + v.y * v.y + v.z * v.z + v.w * v.w;
    }
    cn[e] = s;
}

// NO waves-per-EU floor: zr[64] must live in real VGPRs. With
// __launch_bounds__(256,4) the compiler capped VGPR at 64 and put zr in
// AGPRs -> one v_accvgpr_read per FMA = 2x VALU instructions (round-1 PM).
__global__ __launch_bounds__(TPB) void argmin_kernel(
        const float* __restrict__ z, const float* __restrict__ cb,
        const float* __restrict__ cn, unsigned long long* __restrict__ merge) {
    __shared__ float lcb[CHUNK * DIM];
    __shared__ float lcn[CHUNK];

    int vb  = blockIdx.x / SPLIT;   // voxel block 0..127
    int sp  = blockIdx.x % SPLIT;   // codebook split 0..7
    int vox = vb * TPB + threadIdx.x;

    float4 zr[DIM / 4];
    const float4* zrow = (const float4*)(z + (size_t)vox * DIM);
#pragma unroll
    for (int i = 0; i < DIM / 4; ++i) zr[i] = zrow[i];

    float best = INFINITY;
    int   bidx = 0;
    const int ebase = sp * EPB;

    for (int c = 0; c < EPB; c += CHUNK) {
        // cooperative stage: CHUNK rows -> LDS (coalesced float4)
        const float4* src = (const float4*)(cb + (size_t)(ebase + c) * DIM);
        float4* dst = (float4*)lcb;
#pragma unroll
        for (int i = 0; i < (CHUNK * DIM / 4) / TPB; ++i)   // 8 per thread
            dst[i * TPB + threadIdx.x] = src[i * TPB + threadIdx.x];
        if (threadIdx.x < CHUNK) lcn[threadIdx.x] = cn[ebase + c + threadIdx.x];
        __syncthreads();

#pragma unroll 4
        for (int e = 0; e < CHUNK; ++e) {
            const float4* crow = (const float4*)(lcb + e * DIM);
            float a0 = 0.f, a1 = 0.f, a2 = 0.f, a3 = 0.f;
#pragma unroll
            for (int i = 0; i < DIM / 4; ++i) {
                float4 c4 = crow[i];             // wave-uniform LDS broadcast
                a0 = fmaf(c4.x, zr[i].x, a0);
                a1 = fmaf(c4.y, zr[i].y, a1);
                a2 = fmaf(c4.z, zr[i].z, a2);
                a3 = fmaf(c4.w, zr[i].w, a3);
            }
            float dist = fmaf(-2.f, (a0 + a1) + (a2 + a3), lcn[e]);
            if (dist < best) { best = dist; bidx = ebase + c + e; }
        }
        __syncthreads();
    }

    unsigned long long key = ((unsigned long long)fmap(best) << 32) | (unsigned)bidx;
    atomicMin(&merge[vox], key);
}

__global__ void gather_kernel(const float* __restrict__ z, const int* __restrict__ zc,
        const float* __restrict__ cb, const unsigned long long* __restrict__ merge,
        float* __restrict__ out, unsigned* __restrict__ counts, float* __restrict__ sqsum) {
    int vox = blockIdx.x * blockDim.x + threadIdx.x;
    unsigned idx = (unsigned)(merge[vox] & 0xFFFFFFFFull);

    const float4* crow = (const float4*)(cb + (size_t)idx * DIM);
    const float4* zrow = (const float4*)(z + (size_t)vox * DIM);
    float4* qrow = (float4*)(out + OFF_Q + (size_t)vox * DIM);

    float s = 0.f;
#pragma unroll
    for (int i = 0; i < DIM / 4; ++i) {
        float4 c4 = crow[i];
        float4 z4 = zrow[i];
        float dx = z4.x - c4.x, dy = z4.y - c4.y;
        float dz = z4.z - c4.z, dw = z4.w - c4.w;
        s += dx * dx + dy * dy + dz * dz + dw * dw;
        qrow[i] = c4;
    }
    out[OFF_IDX + vox] = (float)idx;

    int b = zc[vox * 4];
    atomicAdd(&counts[b * NUM_EMB + idx], 1u);

    // block-reduce s, one float atomicAdd per block
#pragma unroll
    for (int o = 32; o > 0; o >>= 1) s += __shfl_down(s, o, 64);
    __shared__ float red[TPB / 64];
    if ((threadIdx.x & 63) == 0) red[threadIdx.x >> 6] = s;
    __syncthreads();
    if (threadIdx.x == 0) {
        float t = red[0] + red[1] + red[2] + red[3];
        atomicAdd(sqsum, t);
    }
}

__global__ void stats_kernel(const unsigned* __restrict__ counts, float* __restrict__ stats) {
    int b = blockIdx.x;
    const unsigned* c = counts + b * NUM_EMB;

    __shared__ float sred[TPB / 64];
    // pass 1: n = total count for this batch
    float nf = 0.f;
    for (int i = threadIdx.x; i < NUM_EMB; i += TPB) nf += (float)c[i];
#pragma unroll
    for (int o = 32; o > 0; o >>= 1) nf += __shfl_down(nf, o, 64);
    if ((threadIdx.x & 63) == 0) sred[threadIdx.x >> 6] = nf;
    __syncthreads();
    float n = sred[0] + sred[1] + sred[2] + sred[3];
    __syncthreads();

    // pass 2: entropy & unique
    float ent = 0.f, uniq = 0.f;
    for (int i = threadIdx.x; i < NUM_EMB; i += TPB) {
        unsigned ci = c[i];
        if (ci) {
            float p = (float)ci / n;
            ent -= p * logf(p + 1e-10f);
            uniq += 1.f;
        }
    }
#pragma unroll
    for (int o = 32; o > 0; o >>= 1) {
        ent  += __shfl_down(ent, o, 64);
        uniq += __shfl_down(uniq, o, 64);
    }
    __shared__ float e4[TPB / 64], u4[TPB / 64];
    if ((threadIdx.x & 63) == 0) { e4[threadIdx.x >> 6] = ent; u4[threadIdx.x >> 6] = uniq; }
    __syncthreads();
    if (threadIdx.x == 0) {
        stats[b]     = e4[0] + e4[1] + e4[2] + e4[3];
        stats[4 + b] = u4[0] + u4[1] + u4[2] + u4[3];
    }
}

__global__ void finalize_kernel(const float* __restrict__ stats,
                                const float* __restrict__ sqsum,
                                float* __restrict__ out) {
    float loss = *sqsum / (float)((size_t)NVOX * DIM);
    float ae = 0.f, ap = 0.f, au = 0.f;
#pragma unroll
    for (int b = 0; b < NBATCH; ++b) {
        ae += stats[b];
        ap += expf(stats[b]);
        au += stats[4 + b];
    }
    ae *= (1.f / NBATCH); ap *= (1.f / NBATCH); au *= (1.f / NBATCH);
    out[OFF_VQ]   = loss;
    out[OFF_COMM] = loss;
    out[OFF_PERP] = ap;
    out[OFF_ENT]  = ae;
    out[OFF_UNIQ] = au;
    out[OFF_UTIL] = au / (float)NUM_EMB * 100.f;
}

extern "C" void kernel_launch(void* const* d_in, const int* in_sizes, int n_in,
                              void* d_out, int out_size, void* d_ws, size_t ws_size,
                              hipStream_t stream) {
    const float* z  = (const float*)d_in[0];
    const int*   zc = (const int*)d_in[1];
    const float* cb = (const float*)d_in[2];
    float* out = (float*)d_out;
    char* ws = (char*)d_ws;

    unsigned long long* merge = (unsigned long long*)ws;        // 32768*8 = 262144 B
    unsigned* counts = (unsigned*)(ws + 262144);                // 4*8192*4 = 131072 B
    float* cn    = (float*)(ws + 393216);                       // 8192*4 = 32768 B
    float* sqsum = (float*)(ws + 425984);                       // 4 B
    float* stats = (float*)(ws + 425988);                       // 8*4 = 32 B

    hipMemsetAsync(merge, 0xFF, 262144, stream);                // u64 max sentinel
    hipMemsetAsync(counts, 0, 131072 + 32768 + 4 + 32, stream); // counts/cn/sqsum/stats

    cnorm_kernel<<<NUM_EMB / TPB, TPB, 0, stream>>>(cb, cn);
    argmin_kernel<<<(NVOX / TPB) * SPLIT, TPB, 0, stream>>>(z, cb, cn, merge);
    gather_kernel<<<NVOX / TPB, TPB, 0, stream>>>(z, zc, cb, merge, out, counts, sqsum);
    stats_kernel<<<NBATCH, TPB, 0, stream>>>(counts, stats);
    finalize_kernel<<<1, 1, 0, stream>>>(stats, sqsum, out);
}

// Round 3
// 244.999 us; speedup vs baseline: 4.3171x; 4.3171x over previous
//
#include <hip/hip_runtime.h>
#include <math.h>

#define NUM_EMB 8192
#define DIM     64
#define NBATCH  4
#define NVOX    32768
#define TPB     256

// output layout (f32, concatenated in return order)
#define OFF_Q     0            // 32768*64
#define OFF_VQ    2097152
#define OFF_COMM  2097153
#define OFF_IDX   2097154      // 32768
#define OFF_PERP  2129922
#define OFF_ENT   2129923
#define OFF_UNIQ  2129924
#define OFF_UTIL  2129925

typedef __bf16 bf16x8 __attribute__((ext_vector_type(8)));
typedef float  f32x4  __attribute__((ext_vector_type(4)));

__device__ __forceinline__ unsigned short f2bf(float f) {   // RNE f32->bf16
    unsigned u = __float_as_uint(f);
    unsigned r = u + 0x7FFFu + ((u >> 16) & 1u);
    return (unsigned short)(r >> 16);
}
__device__ __forceinline__ float bf2f(unsigned short h) {
    return __uint_as_float(((unsigned)h) << 16);
}

// elementwise 3-way bf16 split of the codebook: cb = h + m + l (+ 2^-27 residual)
__global__ void splitcb_kernel(const float* __restrict__ cb,
                               unsigned short* __restrict__ h,
                               unsigned short* __restrict__ m,
                               unsigned short* __restrict__ l) {
    int i = blockIdx.x * blockDim.x + threadIdx.x;   // < 8192*64
    float f = cb[i];
    unsigned short hh = f2bf(f);  float r1 = f  - bf2f(hh);
    unsigned short mm = f2bf(r1); float r2 = r1 - bf2f(mm);
    h[i] = hh; m[i] = mm; l[i] = f2bf(r2);
}

__global__ void cnorm_kernel(const float* __restrict__ cb, float* __restrict__ cn) {
    int e = blockIdx.x * blockDim.x + threadIdx.x;
    const float4* row = (const float4*)(cb + (size_t)e * DIM);
    float s = 0.f;
#pragma unroll
    for (int i = 0; i < DIM / 4; ++i) {
        float4 v = row[i];
        s += v.x * v.x + v.y * v.y + v.z * v.z + v.w * v.w;
    }
    cn[e] = s;
}

// MFMA argmin: dist' = ||c||^2 - 2 z.c  via 6-product bf16 split GEMM.
// 512 blocks x 4 waves; 16 voxel rows per wave; full 8192-entry scan per wave.
__global__ __launch_bounds__(TPB, 2) void argmin_mfma_kernel(
        const float* __restrict__ z,
        const unsigned short* __restrict__ cbh,
        const unsigned short* __restrict__ cbm,
        const unsigned short* __restrict__ cbl,
        const float* __restrict__ cn,
        unsigned* __restrict__ bestidx, float* __restrict__ outidx) {
    __shared__ __align__(16) char lcb[3 * 16384];   // 3 splits x 128 entries x 128B
    __shared__ float lcn[128];

    const int t  = threadIdx.x;
    const int l  = t & 63, w = t >> 6;
    const int lc = l & 15, lg = l >> 4;

    // A fragments: on-the-fly 3-split of this wave's 16 z rows.
    // lane l holds A[row=lc][k = lg*8 + j (+32 per k-step)] -- 8 contiguous f32.
    const int arow = blockIdx.x * 64 + w * 16 + lc;
    const float* zp = z + (size_t)arow * DIM + lg * 8;
    union U { bf16x8 v; unsigned short s[8]; };
    U Ah[2], Am[2], Al[2];
#pragma unroll
    for (int ks = 0; ks < 2; ++ks)
#pragma unroll
        for (int j = 0; j < 8; ++j) {
            float f = zp[ks * 32 + j];
            unsigned short hh = f2bf(f);  float r1 = f  - bf2f(hh);
            unsigned short mm = f2bf(r1); float r2 = r1 - bf2f(mm);
            Ah[ks].s[j] = hh; Am[ks].s[j] = mm; Al[ks].s[j] = f2bf(r2);
        }

    float    m1[4] = {INFINITY, INFINITY, INFINITY, INFINITY};
    unsigned i1[4] = {0, 0, 0, 0};

    for (int ch = 0; ch < NUM_EMB / 128; ++ch) {
        // stage 3x16KB codebook split chunk, XOR-swizzled (row&7)<<4 on byte addr
#pragma unroll
        for (int s = 0; s < 3; ++s) {
            const char* src = (const char*)(s == 0 ? cbh : s == 1 ? cbm : cbl)
                              + (size_t)ch * 16384;
#pragma unroll
            for (int j = 0; j < 4; ++j) {
                int off = (j * 256 + t) * 16;
                int swz = off ^ (((off >> 7) & 7) << 4);
                *(uint4*)(lcb + s * 16384 + swz) = *(const uint4*)(src + off);
            }
        }
        if (t < 128) lcn[t] = cn[ch * 128 + t];
        __syncthreads();

        for (int tile = 0; tile < 8; ++tile) {
            int ecol = tile * 16 + lc;                 // entry within chunk
            float cnv = lcn[ecol];
            int a0 = ecol * 128 + lg * 16;             // B^T row-major byte addr
            int sx = (ecol & 7) << 4;
            int s0 = a0 ^ sx, s1 = (a0 + 64) ^ sx;     // k-step 0 / 1
            bf16x8 bh0 = *(const bf16x8*)(lcb + s0);
            bf16x8 bh1 = *(const bf16x8*)(lcb + s1);
            bf16x8 bm0 = *(const bf16x8*)(lcb + 16384 + s0);
            bf16x8 bm1 = *(const bf16x8*)(lcb + 16384 + s1);
            bf16x8 bl0 = *(const bf16x8*)(lcb + 32768 + s0);
            bf16x8 bl1 = *(const bf16x8*)(lcb + 32768 + s1);
            f32x4 acc0 = {0.f, 0.f, 0.f, 0.f}, acc1 = {0.f, 0.f, 0.f, 0.f};
            // 6 products with weight >= 2^-18, split over 2 indep accumulators
            acc0 = __builtin_amdgcn_mfma_f32_16x16x32_bf16(Ah[0].v, bh0, acc0, 0, 0, 0);
            acc1 = __builtin_amdgcn_mfma_f32_16x16x32_bf16(Ah[1].v, bh1, acc1, 0, 0, 0);
            acc0 = __builtin_amdgcn_mfma_f32_16x16x32_bf16(Ah[0].v, bm0, acc0, 0, 0, 0);
            acc1 = __builtin_amdgcn_mfma_f32_16x16x32_bf16(Ah[1].v, bm1, acc1, 0, 0, 0);
            acc0 = __builtin_amdgcn_mfma_f32_16x16x32_bf16(Am[0].v, bh0, acc0, 0, 0, 0);
            acc1 = __builtin_amdgcn_mfma_f32_16x16x32_bf16(Am[1].v, bh1, acc1, 0, 0, 0);
            acc0 = __builtin_amdgcn_mfma_f32_16x16x32_bf16(Ah[0].v, bl0, acc0, 0, 0, 0);
            acc1 = __builtin_amdgcn_mfma_f32_16x16x32_bf16(Ah[1].v, bl1, acc1, 0, 0, 0);
            acc0 = __builtin_amdgcn_mfma_f32_16x16x32_bf16(Am[0].v, bm0, acc0, 0, 0, 0);
            acc1 = __builtin_amdgcn_mfma_f32_16x16x32_bf16(Am[1].v, bm1, acc1, 0, 0, 0);
            acc0 = __builtin_amdgcn_mfma_f32_16x16x32_bf16(Al[0].v, bh0, acc0, 0, 0, 0);
            acc1 = __builtin_amdgcn_mfma_f32_16x16x32_bf16(Al[1].v, bh1, acc1, 0, 0, 0);
            unsigned eidx = ch * 128 + ecol;
#pragma unroll
            for (int r = 0; r < 4; ++r) {              // D: col=lc, row=lg*4+r (m89)
                float d = fmaf(-2.f, acc0[r] + acc1[r], cnv);
                if (d < m1[r]) { m1[r] = d; i1[r] = eidx; }
            }
        }
        __syncthreads();
    }

    // reduce across the 16 column-lanes of each group (tiebreak: lowest index)
#pragma unroll
    for (int r = 0; r < 4; ++r)
#pragma unroll
        for (int st = 1; st < 16; st <<= 1) {
            float    om = __shfl_xor(m1[r], st, 16);
            unsigned oi = (unsigned)__shfl_xor((int)i1[r], st, 16);
            if (om < m1[r] || (om == m1[r] && oi < i1[r])) { m1[r] = om; i1[r] = oi; }
        }
    if (lc == 0)
#pragma unroll
        for (int r = 0; r < 4; ++r) {
            int vox = blockIdx.x * 64 + w * 16 + lg * 4 + r;
            bestidx[vox] = i1[r];
            outidx[vox]  = (float)i1[r];
        }
}

__global__ void gather_kernel(const float* __restrict__ z, const int* __restrict__ zc,
        const float* __restrict__ cb, const unsigned* __restrict__ bestidx,
        float* __restrict__ out, unsigned* __restrict__ counts, float* __restrict__ sqsum) {
    int vox = blockIdx.x * blockDim.x + threadIdx.x;
    unsigned idx = bestidx[vox];

    const float4* crow = (const float4*)(cb + (size_t)idx * DIM);
    const float4* zrow = (const float4*)(z + (size_t)vox * DIM);
    float4* qrow = (float4*)(out + OFF_Q + (size_t)vox * DIM);

    float s = 0.f;
#pragma unroll
    for (int i = 0; i < DIM / 4; ++i) {
        float4 c4 = crow[i];
        float4 z4 = zrow[i];
        float dx = z4.x - c4.x, dy = z4.y - c4.y;
        float dz = z4.z - c4.z, dw = z4.w - c4.w;
        s += dx * dx + dy * dy + dz * dz + dw * dw;
        qrow[i] = c4;
    }

    int b = zc[vox * 4];
    atomicAdd(&counts[b * NUM_EMB + idx], 1u);

#pragma unroll
    for (int o = 32; o > 0; o >>= 1) s += __shfl_down(s, o, 64);
    __shared__ float red[TPB / 64];
    if ((threadIdx.x & 63) == 0) red[threadIdx.x >> 6] = s;
    __syncthreads();
    if (threadIdx.x == 0) {
        float tt = red[0] + red[1] + red[2] + red[3];
        atomicAdd(sqsum, tt);
    }
}

__global__ void stats_kernel(const unsigned* __restrict__ counts, float* __restrict__ stats) {
    int b = blockIdx.x;
    const unsigned* c = counts + b * NUM_EMB;

    __shared__ float sred[TPB / 64];
    float nf = 0.f;
    for (int i = threadIdx.x; i < NUM_EMB; i += TPB) nf += (float)c[i];
#pragma unroll
    for (int o = 32; o > 0; o >>= 1) nf += __shfl_down(nf, o, 64);
    if ((threadIdx.x & 63) == 0) sred[threadIdx.x >> 6] = nf;
    __syncthreads();
    float n = sred[0] + sred[1] + sred[2] + sred[3];
    __syncthreads();

    float ent = 0.f, uniq = 0.f;
    for (int i = threadIdx.x; i < NUM_EMB; i += TPB) {
        unsigned ci = c[i];
        if (ci) {
            float p = (float)ci / n;
            ent -= p * logf(p + 1e-10f);
            uniq += 1.f;
        }
    }
#pragma unroll
    for (int o = 32; o > 0; o >>= 1) {
        ent  += __shfl_down(ent, o, 64);
        uniq += __shfl_down(uniq, o, 64);
    }
    __shared__ float e4[TPB / 64], u4[TPB / 64];
    if ((threadIdx.x & 63) == 0) { e4[threadIdx.x >> 6] = ent; u4[threadIdx.x >> 6] = uniq; }
    __syncthreads();
    if (threadIdx.x == 0) {
        stats[b]     = e4[0] + e4[1] + e4[2] + e4[3];
        stats[4 + b] = u4[0] + u4[1] + u4[2] + u4[3];
    }
}

__global__ void finalize_kernel(const float* __restrict__ stats,
                                const float* __restrict__ sqsum,
                                float* __restrict__ out) {
    float loss = *sqsum / (float)((size_t)NVOX * DIM);
    float ae = 0.f, ap = 0.f, au = 0.f;
#pragma unroll
    for (int b = 0; b < NBATCH; ++b) {
        ae += stats[b];
        ap += expf(stats[b]);
        au += stats[4 + b];
    }
    ae *= (1.f / NBATCH); ap *= (1.f / NBATCH); au *= (1.f / NBATCH);
    out[OFF_VQ]   = loss;
    out[OFF_COMM] = loss;
    out[OFF_PERP] = ap;
    out[OFF_ENT]  = ae;
    out[OFF_UNIQ] = au;
    out[OFF_UTIL] = au / (float)NUM_EMB * 100.f;
}

extern "C" void kernel_launch(void* const* d_in, const int* in_sizes, int n_in,
                              void* d_out, int out_size, void* d_ws, size_t ws_size,
                              hipStream_t stream) {
    const float* z  = (const float*)d_in[0];
    const int*   zc = (const int*)d_in[1];
    const float* cb = (const float*)d_in[2];
    float* out = (float*)d_out;
    char* ws = (char*)d_ws;

    // codebook splits live in the d_out Q-region as scratch (3 MB of 8 MB);
    // gather_kernel fully overwrites Q afterwards, so d_out validation is safe.
    unsigned short* cbh = (unsigned short*)(out + OFF_Q);
    unsigned short* cbm = cbh + NUM_EMB * DIM;
    unsigned short* cbl = cbm + NUM_EMB * DIM;

    unsigned* counts  = (unsigned*)ws;                 // 131072 B
    float*    cn      = (float*)(ws + 131072);         // 32768 B
    unsigned* bestidx = (unsigned*)(ws + 163840);      // 131072 B
    float*    sqsum   = (float*)(ws + 294912);         // 4 B
    float*    stats   = (float*)(ws + 294916);         // 32 B

    hipMemsetAsync(counts, 0, 131072, stream);
    hipMemsetAsync(sqsum, 0, 36, stream);

    splitcb_kernel<<<(NUM_EMB * DIM) / TPB, TPB, 0, stream>>>(cb, cbh, cbm, cbl);
    cnorm_kernel<<<NUM_EMB / TPB, TPB, 0, stream>>>(cb, cn);
    argmin_mfma_kernel<<<NVOX / 64, TPB, 0, stream>>>(z, cbh, cbm, cbl, cn,
                                                      bestidx, out + OFF_IDX);
    gather_kernel<<<NVOX / TPB, TPB, 0, stream>>>(z, zc, cb, bestidx, out, counts, sqsum);
    stats_kernel<<<NBATCH, TPB, 0, stream>>>(counts, stats);
    finalize_kernel<<<1, 1, 0, stream>>>(stats, sqsum, out);
}